// Round 1
// baseline (193.757 us; speedup 1.0000x reference)
//
#include <hip/hip_runtime.h>
#include <math.h>

#define GAMMA_F 1.4f
#define EPS_F 1e-6f
#define B_ 16
#define K_ 64
#define NT_ 128
#define NX_ 256
#define NI 63            // K-1 interfaces
#define N_NEWTON 20

// ---------------------------------------------------------------------------
// wave_f_df exactly as reference (clip(x, EPS) == max(x, EPS))
// ---------------------------------------------------------------------------
__device__ __forceinline__ void wave_f_df(float p, float p_K, float A_K, float B_K,
                                          float c_K, float& f, float& df) {
    const float gm1 = GAMMA_F - 1.0f;
    const float gp1 = GAMMA_F + 1.0f;
    const float exp_rare = gm1 / (2.0f * GAMMA_F);
    float denom = fmaxf(p + B_K, EPS_F);
    float sqrt_AoD = sqrtf(fmaxf(A_K / denom, EPS_F));
    float f_shock = (p - p_K) * sqrt_AoD;
    float df_shock = sqrt_AoD * (1.0f - (p - p_K) / (2.0f * denom));
    float pKc = fmaxf(p_K, EPS_F);
    float p_ratio = fmaxf(p / pKc, EPS_F);
    float f_rare = 2.0f * c_K / gm1 * (powf(p_ratio, exp_rare) - 1.0f);
    float df_rare = c_K / (GAMMA_F * pKc) * powf(p_ratio, -gp1 / (2.0f * GAMMA_F));
    bool is_shock = p > p_K;
    f = is_shock ? f_shock : f_rare;
    df = is_shock ? df_shock : df_rare;
}

// ---------------------------------------------------------------------------
// Kernel A: one thread per (batch, interface). 16 blocks x 64 threads.
// Writes speed_right, speed_left, x_d into workspace.
// ---------------------------------------------------------------------------
__global__ void riemann_solve_kernel(const float* __restrict__ xs,
                                     const float* __restrict__ ks,
                                     const float* __restrict__ ks_v,
                                     const float* __restrict__ ks_p,
                                     float* __restrict__ sr_ws,
                                     float* __restrict__ sl_ws,
                                     float* __restrict__ xd_ws) {
    const int b = blockIdx.x;
    const int i = threadIdx.x;
    if (i >= NI) return;

    const float gm1 = GAMMA_F - 1.0f;
    const float gp1 = GAMMA_F + 1.0f;
    const float exp_rare = gm1 / (2.0f * GAMMA_F);

    const int base = b * K_ + i;
    float rho_L = ks[base],     rho_R = ks[base + 1];
    float u_L   = ks_v[base],   u_R   = ks_v[base + 1];
    float p_L   = ks_p[base],   p_R   = ks_p[base + 1];

    float c_L = sqrtf(fmaxf(GAMMA_F * p_L / fmaxf(rho_L, EPS_F), EPS_F));
    float c_R = sqrtf(fmaxf(GAMMA_F * p_R / fmaxf(rho_R, EPS_F), EPS_F));
    float A_L = 2.0f / (gp1 * fmaxf(rho_L, EPS_F));
    float A_R = 2.0f / (gp1 * fmaxf(rho_R, EPS_F));
    float B_L = gm1 / gp1 * p_L;
    float B_R = gm1 / gp1 * p_R;

    // initial guess (two-rarefaction)
    float num = c_L + c_R - 0.5f * gm1 * (u_R - u_L);
    float den = c_L / powf(fmaxf(p_L, EPS_F), exp_rare)
              + c_R / powf(fmaxf(p_R, EPS_F), exp_rare);
    float p_star = fmaxf(powf(num / den, 1.0f / exp_rare), EPS_F);

    #pragma unroll 1
    for (int it = 0; it < N_NEWTON; ++it) {
        float fL, dfL, fR, dfR;
        wave_f_df(p_star, p_L, A_L, B_L, c_L, fL, dfL);
        wave_f_df(p_star, p_R, A_R, B_R, c_R, fR, dfR);
        float residual = fL + fR + (u_R - u_L);
        float jac = fmaxf(dfL + dfR, EPS_F);
        p_star = fmaxf(p_star - residual / jac, EPS_F);
    }

    const float gp1_o_2g = gp1 / (2.0f * GAMMA_F);
    float s1 = u_L - c_L * sqrtf(fmaxf(1.0f + gp1_o_2g * (p_star / fmaxf(p_L, EPS_F) - 1.0f), EPS_F));
    float speed_left = (p_star > p_L) ? s1 : (u_L - c_L);
    float s3 = u_R + c_R * sqrtf(fmaxf(1.0f + gp1_o_2g * (p_star / fmaxf(p_R, EPS_F) - 1.0f), EPS_F));
    float speed_right = (p_star > p_R) ? s3 : (u_R + c_R);

    sl_ws[base] = speed_left;
    sr_ws[base] = speed_right;
    xd_ws[base] = xs[b * (K_ + 1) + i + 1];   // xs[:, 1:K]
}

// ---------------------------------------------------------------------------
// Kernel B: bias field. 256 threads/block, 16 points/block, each thread
// produces 4 consecutive k outputs and stores a float4 (coalesced).
// grid = B * (NT*NX/16) = 16 * 2048 = 32768 blocks.
// ---------------------------------------------------------------------------
__global__ __launch_bounds__(256) void
bias_kernel(const float* __restrict__ t_coords,
            const float* __restrict__ x_coords,
            const float* __restrict__ pieces_mask,
            const float* __restrict__ sr_ws,
            const float* __restrict__ sl_ws,
            const float* __restrict__ xd_ws,
            float* __restrict__ out) {
    __shared__ float s_sr[NI];
    __shared__ float s_sl[NI];
    __shared__ float s_xd[NI];
    __shared__ float s_mask[K_];

    const int bid = blockIdx.x;
    const int b = bid >> 11;            // / (NT*NX/16 = 2048)
    const int blk_in_b = bid & 2047;
    const int tid = threadIdx.x;

    // stage per-batch tables into LDS
    {
        const int g = tid >> 6;         // 0..3
        const int r = tid & 63;
        if (g == 0) { if (r < NI) s_sr[r] = sr_ws[b * K_ + r]; }
        else if (g == 1) { if (r < NI) s_sl[r] = sl_ws[b * K_ + r]; }
        else if (g == 2) { if (r < NI) s_xd[r] = xd_ws[b * K_ + r]; }
        else { s_mask[r] = pieces_mask[b * K_ + r]; }
    }
    __syncthreads();

    const int p_local = tid >> 4;       // 0..15, point within block
    const int j = tid & 15;             // k-quad index, k0 = 4*j
    const int pt = (blk_in_b << 4) + p_local;       // 0..NT*NX-1
    const long long pbase = (long long)b * (NT_ * NX_) + pt;

    const float t = t_coords[pbase];
    const float x = x_coords[pbase];
    const float inv_t = 1.0f / (t + EPS_F);

    const int k0 = j << 2;
    float res[4];
    #pragma unroll
    for (int q = 0; q < 4; ++q) {
        const int k = k0 + q;
        float pl = 0.0f, pr = 0.0f;
        if (k < NI) {                                // pad_last: PL[k], 0 at k=K-1
            float xi = (x - s_xd[k]) * inv_t;
            pl = fmaxf(xi - s_sr[k], 0.0f);
        }
        if (k >= 1) {                                // pad_first: PR[k-1], 0 at k=0
            float xi = (x - s_xd[k - 1]) * inv_t;
            pr = fmaxf(s_sl[k - 1] - xi, 0.0f);
        }
        float bias = -(pl + pr);
        float m = s_mask[k];
        res[q] = bias * m + ((m == 0.0f) ? -1.0e9f : 0.0f);
    }

    float4* outv = reinterpret_cast<float4*>(out + pbase * K_ + k0);
    *outv = make_float4(res[0], res[1], res[2], res[3]);
}

// ---------------------------------------------------------------------------
extern "C" void kernel_launch(void* const* d_in, const int* in_sizes, int n_in,
                              void* d_out, int out_size, void* d_ws, size_t ws_size,
                              hipStream_t stream) {
    const float* xs          = (const float*)d_in[0];
    const float* ks          = (const float*)d_in[1];
    const float* ks_v        = (const float*)d_in[2];
    const float* ks_p        = (const float*)d_in[3];
    const float* pieces_mask = (const float*)d_in[4];
    const float* t_coords    = (const float*)d_in[5];
    const float* x_coords    = (const float*)d_in[6];
    float* out = (float*)d_out;

    float* ws = (float*)d_ws;
    float* sr_ws = ws;                  // B*K floats
    float* sl_ws = ws + B_ * K_;        // B*K floats
    float* xd_ws = ws + 2 * B_ * K_;    // B*K floats

    riemann_solve_kernel<<<B_, 64, 0, stream>>>(xs, ks, ks_v, ks_p, sr_ws, sl_ws, xd_ws);

    const int blocks = B_ * (NT_ * NX_ / 16);   // 32768
    bias_kernel<<<blocks, 256, 0, stream>>>(t_coords, x_coords, pieces_mask,
                                            sr_ws, sl_ws, xd_ws, out);
}